// Round 21
// baseline (545.658 us; speedup 1.0000x reference)
//
#include <hip/hip_runtime.h>
#include <hip/hip_fp16.h>

#define DIM 64
#define PROWS 1024          // rows per partition (localRow fits 10 bits)
#define PSHIFT 10
#define MAXPART 512         // supports nNodes <= 524288 (= 2^19 packing limit)
#define SCHUNK 4096         // edges per block in staged scatter

__device__ __forceinline__ float b2f(ushort u) { return __uint_as_float(((unsigned)u) << 16); }
__device__ __forceinline__ ushort f2b(float x) {           // round-to-nearest-even
    unsigned b = __float_as_uint(x);
    b += 0x7FFFu + ((b >> 16) & 1u);
    return (ushort)(b >> 16);
}
__device__ __forceinline__ unsigned pk(float x, float y) {
    return (unsigned)f2b(x) | ((unsigned)f2b(y) << 16);
}
// val encode: f16 bits >> 2 (exp5+mant8, RNE on the 2 dropped bits). 13 bits.
__device__ __forceinline__ ushort encV(float v) {
    ushort hb = __half_as_ushort(__float2half(v));
    hb = (ushort)(hb + 1u + ((hb >> 2) & 1u));
    return (ushort)(hb >> 2);
}
// val decode from packed csr word (code in bits 31:19)
__device__ __forceinline__ float decV(unsigned k) {
    return __half2float(__ushort_as_half((ushort)((k >> 19) << 2)));
}

// ---------------- partition-level histogram (LDS-aggregated, int4 reads) ------
__global__ __launch_bounds__(256) void k_phist(const int* __restrict__ rows,
                                               int* __restrict__ partCnt,
                                               int nE, int nPart) {
    __shared__ int h[MAXPART];
    for (int t = threadIdx.x; t < nPart; t += 256) h[t] = 0;
    __syncthreads();
    const long tid    = (long)blockIdx.x * blockDim.x + threadIdx.x;
    const long stride = (long)gridDim.x * blockDim.x;
    for (long i = tid * 4; i + 3 < nE; i += stride * 4) {
        int4 r = *(const int4*)(rows + i);
        atomicAdd(&h[r.x >> PSHIFT], 1);
        atomicAdd(&h[r.y >> PSHIFT], 1);
        atomicAdd(&h[r.z >> PSHIFT], 1);
        atomicAdd(&h[r.w >> PSHIFT], 1);
    }
    for (long i = (long)(nE & ~3) + tid; i < nE; i += stride)
        atomicAdd(&h[rows[i] >> PSHIFT], 1);
    __syncthreads();
    for (int t = threadIdx.x; t < nPart; t += 256) {
        int v = h[t];
        if (v) atomicAdd(&partCnt[t], v);
    }
}

// ---------------- single-block scan over partitions (512 wide) ----------------
__global__ __launch_bounds__(512) void k_pscan(const int* __restrict__ partCnt,
                                               int* __restrict__ partStart,
                                               int* __restrict__ partCurPad,
                                               int nPart, int nE) {
    __shared__ int s[512];
    const int t = threadIdx.x;
    int v = (t < nPart) ? partCnt[t] : 0;
    s[t] = v; __syncthreads();
    for (int off = 1; off < 512; off <<= 1) {
        int tmp = (t >= off) ? s[t - off] : 0;
        __syncthreads();
        s[t] += tmp;
        __syncthreads();
    }
    if (t < nPart) {
        int excl = s[t] - v;
        partStart[t] = excl;
        partCurPad[t * 16] = excl;
    }
    if (t == 0) partStart[nPart] = nE;
}

// ---- pass A: COO -> partition-ordered SoA (keyA u32, valA u16 code) ----------
// LDS-staged; copy-out is LINEAR per run -> coalesced. int4/float4 input reads.
__global__ __launch_bounds__(256) void k_scatterS(const int* __restrict__ rows,
                                                  const int* __restrict__ cols,
                                                  const float* __restrict__ vals,
                                                  int* __restrict__ partCurPad,
                                                  unsigned* __restrict__ keyA,
                                                  ushort* __restrict__ valA,
                                                  int nE, int nPart) {
    __shared__ int hist[MAXPART];
    __shared__ int cstart[MAXPART];
    __shared__ int runBase[MAXPART];
    __shared__ int s2[256];
    __shared__ unsigned stageK[SCHUNK];          // 16 KB
    __shared__ ushort   stageV[SCHUNK];          // 8 KB
    __shared__ ushort   partOf[SCHUNK];          // 8 KB
    const int base = blockIdx.x * SCHUNK;
    const int cnt  = min(SCHUNK, nE - base);
    const int t = threadIdx.x;
    int4 rcv[SCHUNK / 1024];                     // 4 x int4 = 16 edges/thread

    for (int j = t; j < MAXPART; j += 256) hist[j] = 0;
    __syncthreads();
    #pragma unroll
    for (int g = 0; g < SCHUNK / 1024; ++g) {
        int i0 = base + g * 1024 + t * 4;
        int4 r;
        if (i0 + 3 < nE) {
            r = *(const int4*)(rows + i0);
        } else {
            r.x = (i0     < nE) ? rows[i0]     : -1;
            r.y = (i0 + 1 < nE) ? rows[i0 + 1] : -1;
            r.z = (i0 + 2 < nE) ? rows[i0 + 2] : -1;
            r.w = (i0 + 3 < nE) ? rows[i0 + 3] : -1;
        }
        rcv[g] = r;
        if (r.x >= 0) atomicAdd(&hist[r.x >> PSHIFT], 1);
        if (r.y >= 0) atomicAdd(&hist[r.y >> PSHIFT], 1);
        if (r.z >= 0) atomicAdd(&hist[r.z >> PSHIFT], 1);
        if (r.w >= 0) atomicAdd(&hist[r.w >> PSHIFT], 1);
    }
    __syncthreads();
    {
        // scan 512 entries with 256 threads (2 per thread)
        int a0 = hist[2 * t], a1 = hist[2 * t + 1];
        s2[t] = a0 + a1; __syncthreads();
        for (int off = 1; off < 256; off <<= 1) {
            int tmp = (t >= off) ? s2[t - off] : 0;
            __syncthreads();
            s2[t] += tmp;
            __syncthreads();
        }
        int excl = s2[t] - (a0 + a1);
        cstart[2 * t]     = excl;
        cstart[2 * t + 1] = excl + a0;
        if (a0) runBase[2 * t]     = atomicAdd(&partCurPad[(2 * t) * 16], a0);
        if (a1) runBase[2 * t + 1] = atomicAdd(&partCurPad[(2 * t + 1) * 16], a1);
    }
    __syncthreads();
    for (int j = t; j < MAXPART; j += 256) hist[j] = 0;   // reuse as rank
    __syncthreads();
    #pragma unroll
    for (int g = 0; g < SCHUNK / 1024; ++g) {
        int i0 = base + g * 1024 + t * 4;
        int4 r = rcv[g];
        int4 c; float4 v;
        if (i0 + 3 < nE) {
            c = *(const int4*)(cols + i0);
            v = *(const float4*)(vals + i0);
        } else {
            c.x = (i0     < nE) ? cols[i0]     : 0;
            c.y = (i0 + 1 < nE) ? cols[i0 + 1] : 0;
            c.z = (i0 + 2 < nE) ? cols[i0 + 2] : 0;
            c.w = (i0 + 3 < nE) ? cols[i0 + 3] : 0;
            v.x = (i0     < nE) ? vals[i0]     : 0.f;
            v.y = (i0 + 1 < nE) ? vals[i0 + 1] : 0.f;
            v.z = (i0 + 2 < nE) ? vals[i0 + 2] : 0.f;
            v.w = (i0 + 3 < nE) ? vals[i0 + 3] : 0.f;
        }
        int   rr[4] = { r.x, r.y, r.z, r.w };
        int   cc[4] = { c.x, c.y, c.z, c.w };
        float vv[4] = { v.x, v.y, v.z, v.w };
        #pragma unroll
        for (int j = 0; j < 4; ++j) {
            if (rr[j] >= 0) {
                int p = rr[j] >> PSHIFT;
                int rank = atomicAdd(&hist[p], 1);
                int slot = cstart[p] + rank;
                stageK[slot] = (((unsigned)(rr[j] & (PROWS - 1))) << 19) | (unsigned)cc[j];
                stageV[slot] = encV(vv[j]);
                partOf[slot] = (ushort)p;
            }
        }
    }
    __syncthreads();
    for (int s = t; s < cnt; s += 256) {
        int p = partOf[s];
        int dst = runBase[p] + (s - cstart[p]);
        keyA[dst] = stageK[s];
        valA[dst] = stageV[s];
    }
}

// ---- fused: row-hist + scan + reorder -> packed CSR (u32: val13|col19) ------
__global__ __launch_bounds__(1024) void k_buildCSR(const int* __restrict__ partStart,
                                                   const unsigned* __restrict__ keyA,
                                                   const ushort* __restrict__ valA,
                                                   unsigned* __restrict__ csr,
                                                   int* __restrict__ rowStart,
                                                   int nNodes, int nE, int nPart) {
    __shared__ int hist[PROWS];
    __shared__ int cur[PROWS];
    __shared__ int s[1024];
    const int p  = blockIdx.x;
    const int r0 = p * PROWS;
    const int segStart = partStart[p], segEnd = partStart[p + 1];
    const int t = threadIdx.x;

    hist[t] = 0;
    __syncthreads();
    for (int i = segStart + t; i < segEnd; i += 1024)
        atomicAdd(&hist[keyA[i] >> 19], 1);
    __syncthreads();

    int a = hist[t];
    s[t] = a;
    __syncthreads();
    for (int off = 1; off < 1024; off <<= 1) {
        int tmp = (t >= off) ? s[t - off] : 0;
        __syncthreads();
        s[t] += tmp;
        __syncthreads();
    }
    cur[t] = segStart + s[t] - a;
    __syncthreads();

    int rN = nNodes - r0; if (rN > PROWS) rN = PROWS;
    if (t < rN) rowStart[r0 + t] = cur[t];
    if (p == nPart - 1 && t == 0) rowStart[nNodes] = nE;
    __syncthreads();

    for (int i = segStart + t; i < segEnd; i += 1024) {
        unsigned k = keyA[i];
        int lr = k >> 19;
        int pos = atomicAdd(&cur[lr], 1);
        csr[pos] = (((unsigned)valA[i]) << 19) | (k & 0x7FFFFu);
    }
}

// ---------------- convert concat(uE,iE) f32 -> bf16 (8 elems/thread) ----------
__global__ __launch_bounds__(256) void k_toBf16(const float* __restrict__ uE,
                                                const float* __restrict__ iE,
                                                ushort* __restrict__ embB,
                                                int nNodes, int nUsers) {
    const long total8 = (long)nNodes * DIM / 8;
    const long user8  = (long)nUsers * DIM / 8;
    for (long i = (long)blockIdx.x * blockDim.x + threadIdx.x; i < total8;
         i += (long)gridDim.x * blockDim.x) {
        const float4* p = (i < user8) ? (const float4*)uE + 2 * i
                                      : (const float4*)iE + 2 * (i - user8);
        float4 a = p[0], b = p[1];
        uint4 o;
        o.x = pk(a.x, a.y); o.y = pk(a.z, a.w);
        o.z = pk(b.x, b.y); o.w = pk(b.z, b.w);
        ((uint4*)embB)[i] = o;
    }
}

// ---------------- SpMM hop1 (bf16 gather, packed u32 edges) -------------------
// cur1B stored via NT store: streaming full-line write, keeps L2 for embB.
__global__ __launch_bounds__(256) void k_spmm1(const int* __restrict__ rowStart,
                                               const unsigned* __restrict__ csr,
                                               const ushort* __restrict__ embB,
                                               ushort* __restrict__ cur1B,
                                               int nNodes) {
    const int lane = threadIdx.x & 63;
    int r = blockIdx.x * (blockDim.x >> 6) + (threadIdx.x >> 6);
    if (r >= nNodes) return;
    int start = __builtin_amdgcn_readfirstlane(rowStart[r]);
    int end   = __builtin_amdgcn_readfirstlane(rowStart[r + 1]);
    float acc = 0.f;
    int e = start;
    for (; e + 7 < end; e += 8) {
        unsigned k[8]; float x[8];
        #pragma unroll
        for (int j = 0; j < 8; ++j) k[j] = csr[e + j];
        #pragma unroll
        for (int j = 0; j < 8; ++j) x[j] = b2f(embB[(size_t)(k[j] & 0x7FFFFu) * DIM + lane]);
        #pragma unroll
        for (int j = 0; j < 8; ++j) acc = fmaf(decV(k[j]), x[j], acc);
    }
    for (; e + 3 < end; e += 4) {
        unsigned k[4]; float x[4];
        #pragma unroll
        for (int j = 0; j < 4; ++j) k[j] = csr[e + j];
        #pragma unroll
        for (int j = 0; j < 4; ++j) x[j] = b2f(embB[(size_t)(k[j] & 0x7FFFFu) * DIM + lane]);
        #pragma unroll
        for (int j = 0; j < 4; ++j) acc = fmaf(decV(k[j]), x[j], acc);
    }
    for (; e < end; ++e) {
        unsigned k = csr[e];
        acc = fmaf(decV(k), b2f(embB[(size_t)(k & 0x7FFFFu) * DIM + lane]), acc);
    }
    __builtin_nontemporal_store(f2b(acc), &cur1B[(size_t)r * DIM + lane]);
}

// ---------------- SpMM hop2 (bf16 gather) + fused epilogue --------------------
// embB epilogue read is NT (sequential, once-per-line); cur1B gathers stay cached.
__global__ __launch_bounds__(256) void k_spmm2(const int* __restrict__ rowStart,
                                               const unsigned* __restrict__ csr,
                                               const ushort* __restrict__ cur1B,
                                               const ushort* __restrict__ embB,
                                               float* __restrict__ out,
                                               int nNodes) {
    const int lane = threadIdx.x & 63;
    int r = blockIdx.x * (blockDim.x >> 6) + (threadIdx.x >> 6);
    if (r >= nNodes) return;
    int start = __builtin_amdgcn_readfirstlane(rowStart[r]);
    int end   = __builtin_amdgcn_readfirstlane(rowStart[r + 1]);
    float acc = 0.f;
    int e = start;
    for (; e + 7 < end; e += 8) {
        unsigned k[8]; float x[8];
        #pragma unroll
        for (int j = 0; j < 8; ++j) k[j] = csr[e + j];
        #pragma unroll
        for (int j = 0; j < 8; ++j) x[j] = b2f(cur1B[(size_t)(k[j] & 0x7FFFFu) * DIM + lane]);
        #pragma unroll
        for (int j = 0; j < 8; ++j) acc = fmaf(decV(k[j]), x[j], acc);
    }
    for (; e + 3 < end; e += 4) {
        unsigned k[4]; float x[4];
        #pragma unroll
        for (int j = 0; j < 4; ++j) k[j] = csr[e + j];
        #pragma unroll
        for (int j = 0; j < 4; ++j) x[j] = b2f(cur1B[(size_t)(k[j] & 0x7FFFFu) * DIM + lane]);
        #pragma unroll
        for (int j = 0; j < 4; ++j) acc = fmaf(decV(k[j]), x[j], acc);
    }
    for (; e < end; ++e) {
        unsigned k = csr[e];
        acc = fmaf(decV(k), b2f(cur1B[(size_t)(k & 0x7FFFFu) * DIM + lane]), acc);
    }
    float em = b2f(__builtin_nontemporal_load(&embB[(size_t)r * DIM + lane]));
    float c1 = b2f(cur1B[(size_t)r * DIM + lane]);
    float o = (em + c1 + acc) * (1.0f / 3.0f);
    __builtin_nontemporal_store(o, &out[(size_t)r * DIM + lane]);
}

// ---------------- fallback (round-1 atomic path) ----------------
__global__ __launch_bounds__(256) void spmm_scatter(
    const int* __restrict__ rows, const int* __restrict__ cols,
    const float* __restrict__ vals, const float* __restrict__ srcU,
    const float* __restrict__ srcI, float* __restrict__ dst,
    float scale, int nEdges, int nUsers)
{
    const int lane = threadIdx.x & 63;
    const int wavesPerBlock = blockDim.x >> 6;
    long wave = (long)blockIdx.x * wavesPerBlock + (threadIdx.x >> 6);
    const long nWaves = (long)gridDim.x * wavesPerBlock;
    for (long e = wave; e < nEdges; e += nWaves) {
        const int r = rows[e];
        const int c = cols[e];
        const float v = vals[e] * scale;
        const float* src;
        if (srcI != nullptr) {
            src = (c < nUsers) ? (srcU + (size_t)c * DIM)
                               : (srcI + (size_t)(c - nUsers) * DIM);
        } else {
            src = srcU + (size_t)c * DIM;
        }
        atomicAdd(dst + (size_t)r * DIM + lane, v * src[lane]);
    }
}

__global__ __launch_bounds__(256) void finalize_base(
    const float* __restrict__ userE, const float* __restrict__ itemE,
    const float* __restrict__ cur1, float* __restrict__ out, int nNodes, int nUsers)
{
    const long total4 = (long)nNodes * DIM / 4;
    const long user4  = (long)nUsers * DIM / 4;
    const float inv3 = 1.0f / 3.0f;
    for (long i = (long)blockIdx.x * blockDim.x + threadIdx.x; i < total4;
         i += (long)gridDim.x * blockDim.x) {
        float4 e = (i < user4) ? ((const float4*)userE)[i]
                               : ((const float4*)itemE)[i - user4];
        float4 c = ((const float4*)cur1)[i];
        float4 o;
        o.x = (e.x + c.x) * inv3; o.y = (e.y + c.y) * inv3;
        o.z = (e.z + c.z) * inv3; o.w = (e.w + c.w) * inv3;
        ((float4*)out)[i] = o;
    }
}

// ----------------------------------------------------------------

static inline size_t align256(size_t x) { return (x + 255) & ~(size_t)255; }

extern "C" void kernel_launch(void* const* d_in, const int* in_sizes, int n_in,
                              void* d_out, int out_size, void* d_ws, size_t ws_size,
                              hipStream_t stream)
{
    const int*   rows  = (const int*)d_in[0];
    const int*   cols  = (const int*)d_in[1];
    const float* vals  = (const float*)d_in[2];
    const float* userE = (const float*)d_in[3];
    const float* itemE = (const float*)d_in[4];
    float* out = (float*)d_out;

    const int nE     = in_sizes[0];
    const int nUsers = in_sizes[3] / DIM;
    const int nItems = in_sizes[4] / DIM;
    const int nNodes = nUsers + nItems;
    const int nPart  = (nNodes + PROWS - 1) / PROWS;

    // ws layout:
    //   [region0: max(keyA+valA, embB+cur1B, cur1_f32-fallback)]
    //   [csr (u32/edge)][rowStart][partStart][partCurPad][partCnt]
    const size_t embBB    = (size_t)nNodes * DIM * sizeof(ushort);   // 38.4 MB
    const size_t cur1BB   = (size_t)nNodes * DIM * sizeof(ushort);   // 38.4 MB
    const size_t cur1F32B = (size_t)nNodes * DIM * sizeof(float);    // fallback
    const size_t keyAB    = (size_t)nE * sizeof(unsigned);           // 32 MB
    const size_t valAOff  = align256(keyAB);
    const size_t soaB     = valAOff + (size_t)nE * sizeof(ushort);   // ~48 MB
    size_t reg0B = embBB + cur1BB;
    if (soaB     > reg0B) reg0B = soaB;
    if (cur1F32B > reg0B) reg0B = cur1F32B;
    const size_t csrOff   = align256(reg0B);
    const size_t csrB     = (size_t)nE * sizeof(unsigned);           // 32 MB
    const size_t rsOff    = align256(csrOff + csrB);
    const size_t rsB      = ((size_t)nNodes + 1) * sizeof(int);
    const size_t psOff    = align256(rsOff + rsB);
    const size_t psB      = ((size_t)MAXPART + 1) * sizeof(int);
    const size_t pcOff    = align256(psOff + psB);
    const size_t pcB      = (size_t)MAXPART * 16 * sizeof(int);
    const size_t cntOff   = align256(pcOff + pcB);
    const size_t cntB     = (size_t)MAXPART * sizeof(int);
    const size_t required = cntOff + cntB;

    char* ws = (char*)d_ws;
    unsigned* keyA    = (unsigned*)ws;               // preprocessing phase
    ushort*   valA    = (ushort*)(ws + valAOff);
    ushort*   embB    = (ushort*)ws;                 // after buildCSR
    ushort*   cur1B   = (ushort*)(ws + embBB);
    float*    cur1F32 = (float*)ws;                  // fallback only
    unsigned* csr     = (unsigned*)(ws + csrOff);

    if (ws_size >= required && nNodes <= MAXPART * PROWS && nNodes < (1 << 19)) {
        int* rowStart   = (int*)(ws + rsOff);
        int* partStart  = (int*)(ws + psOff);
        int* partCurPad = (int*)(ws + pcOff);
        int* partCnt    = (int*)(ws + cntOff);

        const int nChunks = (nE + SCHUNK - 1) / SCHUNK;

        hipMemsetAsync(partCnt, 0, (size_t)nPart * sizeof(int), stream);
        k_phist<<<dim3(512), dim3(256), 0, stream>>>(rows, partCnt, nE, nPart);
        k_pscan<<<dim3(1), dim3(512), 0, stream>>>(partCnt, partStart, partCurPad,
                                                   nPart, nE);
        k_scatterS<<<dim3(nChunks), dim3(256), 0, stream>>>(rows, cols, vals,
                                                            partCurPad, keyA, valA,
                                                            nE, nPart);
        k_buildCSR<<<dim3(nPart), dim3(1024), 0, stream>>>(partStart, keyA, valA, csr,
                                                           rowStart, nNodes, nE, nPart);
        // keyA/valA dead; overwrite region with bf16 node matrix
        k_toBf16<<<dim3(2048), dim3(256), 0, stream>>>(userE, itemE, embB,
                                                       nNodes, nUsers);

        const int rowsPerBlock = 4;
        dim3 sgrid((nNodes + rowsPerBlock - 1) / rowsPerBlock), sblk(256);
        k_spmm1<<<sgrid, sblk, 0, stream>>>(rowStart, csr, embB, cur1B, nNodes);
        k_spmm2<<<sgrid, sblk, 0, stream>>>(rowStart, csr, cur1B, embB, out, nNodes);
    } else {
        // fallback: atomic scatter path (round-1)
        hipMemsetAsync(cur1F32, 0, cur1F32B, stream);
        dim3 blk(256);
        spmm_scatter<<<dim3(4096), blk, 0, stream>>>(rows, cols, vals, userE, itemE,
                                                     cur1F32, 1.0f, nE, nUsers);
        finalize_base<<<dim3(2048), blk, 0, stream>>>(userE, itemE, cur1F32, out,
                                                      nNodes, nUsers);
        spmm_scatter<<<dim3(4096), blk, 0, stream>>>(rows, cols, vals, cur1F32, nullptr,
                                                     out, 1.0f / 3.0f, nE, nUsers);
    }
}

// Round 22
// 526.923 us; speedup vs baseline: 1.0356x; 1.0356x over previous
//
#include <hip/hip_runtime.h>
#include <hip/hip_fp16.h>

#define DIM 64
#define PROWS 2048          // rows per partition (localRow fits 11 bits)
#define MAXPART 256         // supports nNodes <= 524288 (= 2^19 packing limit)
#define SCHUNK 4096         // edges per block in staged scatter

__device__ __forceinline__ float b2f(ushort u) { return __uint_as_float(((unsigned)u) << 16); }
__device__ __forceinline__ ushort f2b(float x) {           // round-to-nearest-even
    unsigned b = __float_as_uint(x);
    b += 0x7FFFu + ((b >> 16) & 1u);
    return (ushort)(b >> 16);
}
__device__ __forceinline__ unsigned pk(float x, float y) {
    return (unsigned)f2b(x) | ((unsigned)f2b(y) << 16);
}
// val encode: f16 bits >> 2 (exp5+mant8, RNE on the 2 dropped bits). 13 bits.
__device__ __forceinline__ ushort encV(float v) {
    ushort hb = __half_as_ushort(__float2half(v));
    hb = (ushort)(hb + 1u + ((hb >> 2) & 1u));
    return (ushort)(hb >> 2);
}
// val decode from packed csr word (code in bits 31:19)
__device__ __forceinline__ float decV(unsigned k) {
    return __half2float(__ushort_as_half((ushort)((k >> 19) << 2)));
}

// ---------------- partition-level histogram (LDS-aggregated, int4 reads) ------
__global__ __launch_bounds__(256) void k_phist(const int* __restrict__ rows,
                                               int* __restrict__ partCnt,
                                               int nE, int nPart) {
    __shared__ int h[MAXPART];
    for (int t = threadIdx.x; t < nPart; t += 256) h[t] = 0;
    __syncthreads();
    const long tid    = (long)blockIdx.x * blockDim.x + threadIdx.x;
    const long stride = (long)gridDim.x * blockDim.x;
    for (long i = tid * 4; i + 3 < nE; i += stride * 4) {
        int4 r = *(const int4*)(rows + i);
        atomicAdd(&h[r.x >> 11], 1);
        atomicAdd(&h[r.y >> 11], 1);
        atomicAdd(&h[r.z >> 11], 1);
        atomicAdd(&h[r.w >> 11], 1);
    }
    for (long i = (long)(nE & ~3) + tid; i < nE; i += stride)
        atomicAdd(&h[rows[i] >> 11], 1);
    __syncthreads();
    for (int t = threadIdx.x; t < nPart; t += 256) {
        int v = h[t];
        if (v) atomicAdd(&partCnt[t], v);
    }
}

// ---------------- single-block scan over partitions ----------------
__global__ __launch_bounds__(256) void k_pscan(const int* __restrict__ partCnt,
                                               int* __restrict__ partStart,
                                               int* __restrict__ partCurPad,
                                               int nPart, int nE) {
    __shared__ int s[256];
    const int t = threadIdx.x;
    int v = (t < nPart) ? partCnt[t] : 0;
    s[t] = v; __syncthreads();
    for (int off = 1; off < 256; off <<= 1) {
        int tmp = (t >= off) ? s[t - off] : 0;
        __syncthreads();
        s[t] += tmp;
        __syncthreads();
    }
    if (t < nPart) {
        int excl = s[t] - v;
        partStart[t] = excl;
        partCurPad[t * 16] = excl;
    }
    if (t == 0) partStart[nPart] = nE;
}

// ---- pass A: COO -> partition-ordered SoA (keyA u32, valA u16 code) ----------
// LDS-staged; copy-out is LINEAR per run -> coalesced. int4/float4 input reads.
__global__ __launch_bounds__(256) void k_scatterS(const int* __restrict__ rows,
                                                  const int* __restrict__ cols,
                                                  const float* __restrict__ vals,
                                                  int* __restrict__ partCurPad,
                                                  unsigned* __restrict__ keyA,
                                                  ushort* __restrict__ valA,
                                                  int nE, int nPart) {
    __shared__ int hist[MAXPART];
    __shared__ int cstart[MAXPART];
    __shared__ int runBase[MAXPART];
    __shared__ int s2[256];
    __shared__ unsigned stageK[SCHUNK];          // 16 KB
    __shared__ ushort   stageV[SCHUNK];          // 8 KB
    __shared__ unsigned char partOf[SCHUNK];     // 4 KB
    const int base = blockIdx.x * SCHUNK;
    const int cnt  = min(SCHUNK, nE - base);
    const int t = threadIdx.x;
    int4 rcv[SCHUNK / 1024];                     // 4 x int4 = 16 edges/thread

    for (int j = t; j < nPart; j += 256) hist[j] = 0;
    __syncthreads();
    #pragma unroll
    for (int g = 0; g < SCHUNK / 1024; ++g) {
        int i0 = base + g * 1024 + t * 4;
        int4 r;
        if (i0 + 3 < nE) {
            r = *(const int4*)(rows + i0);
        } else {
            r.x = (i0     < nE) ? rows[i0]     : -1;
            r.y = (i0 + 1 < nE) ? rows[i0 + 1] : -1;
            r.z = (i0 + 2 < nE) ? rows[i0 + 2] : -1;
            r.w = (i0 + 3 < nE) ? rows[i0 + 3] : -1;
        }
        rcv[g] = r;
        if (r.x >= 0) atomicAdd(&hist[r.x >> 11], 1);
        if (r.y >= 0) atomicAdd(&hist[r.y >> 11], 1);
        if (r.z >= 0) atomicAdd(&hist[r.z >> 11], 1);
        if (r.w >= 0) atomicAdd(&hist[r.w >> 11], 1);
    }
    __syncthreads();
    {
        int v = (t < nPart) ? hist[t] : 0;
        s2[t] = v; __syncthreads();
        for (int off = 1; off < 256; off <<= 1) {
            int tmp = (t >= off) ? s2[t - off] : 0;
            __syncthreads();
            s2[t] += tmp;
            __syncthreads();
        }
        if (t < nPart) {
            cstart[t]  = s2[t] - v;
            runBase[t] = v ? atomicAdd(&partCurPad[t * 16], v) : 0;
        }
    }
    __syncthreads();
    for (int j = t; j < nPart; j += 256) hist[j] = 0;   // reuse as rank
    __syncthreads();
    #pragma unroll
    for (int g = 0; g < SCHUNK / 1024; ++g) {
        int i0 = base + g * 1024 + t * 4;
        int4 r = rcv[g];
        int4 c; float4 v;
        if (i0 + 3 < nE) {
            c = *(const int4*)(cols + i0);
            v = *(const float4*)(vals + i0);
        } else {
            c.x = (i0     < nE) ? cols[i0]     : 0;
            c.y = (i0 + 1 < nE) ? cols[i0 + 1] : 0;
            c.z = (i0 + 2 < nE) ? cols[i0 + 2] : 0;
            c.w = (i0 + 3 < nE) ? cols[i0 + 3] : 0;
            v.x = (i0     < nE) ? vals[i0]     : 0.f;
            v.y = (i0 + 1 < nE) ? vals[i0 + 1] : 0.f;
            v.z = (i0 + 2 < nE) ? vals[i0 + 2] : 0.f;
            v.w = (i0 + 3 < nE) ? vals[i0 + 3] : 0.f;
        }
        int   rr[4] = { r.x, r.y, r.z, r.w };
        int   cc[4] = { c.x, c.y, c.z, c.w };
        float vv[4] = { v.x, v.y, v.z, v.w };
        #pragma unroll
        for (int j = 0; j < 4; ++j) {
            if (rr[j] >= 0) {
                int p = rr[j] >> 11;
                int rank = atomicAdd(&hist[p], 1);
                int slot = cstart[p] + rank;
                stageK[slot] = (((unsigned)(rr[j] & (PROWS - 1))) << 19) | (unsigned)cc[j];
                stageV[slot] = encV(vv[j]);
                partOf[slot] = (unsigned char)p;
            }
        }
    }
    __syncthreads();
    for (int s = t; s < cnt; s += 256) {
        int p = partOf[s];
        int dst = runBase[p] + (s - cstart[p]);
        keyA[dst] = stageK[s];
        valA[dst] = stageV[s];
    }
}

// ---- fused: row-hist + scan + reorder -> packed CSR (u32: val13|col19) ------
__global__ __launch_bounds__(1024) void k_buildCSR(const int* __restrict__ partStart,
                                                   const unsigned* __restrict__ keyA,
                                                   const ushort* __restrict__ valA,
                                                   unsigned* __restrict__ csr,
                                                   int* __restrict__ rowStart,
                                                   int nNodes, int nE, int nPart) {
    __shared__ int hist[PROWS];
    __shared__ int cur[PROWS];
    __shared__ int s[1024];
    const int p  = blockIdx.x;
    const int r0 = p * PROWS;
    const int segStart = partStart[p], segEnd = partStart[p + 1];
    const int t = threadIdx.x;

    hist[t] = 0; hist[t + 1024] = 0;
    __syncthreads();
    for (int i = segStart + t; i < segEnd; i += 1024)
        atomicAdd(&hist[keyA[i] >> 19], 1);
    __syncthreads();

    int a0 = hist[2 * t], a1 = hist[2 * t + 1];
    s[t] = a0 + a1;
    __syncthreads();
    for (int off = 1; off < 1024; off <<= 1) {
        int tmp = (t >= off) ? s[t - off] : 0;
        __syncthreads();
        s[t] += tmp;
        __syncthreads();
    }
    int pairExcl = s[t] - (a0 + a1);
    cur[2 * t]     = segStart + pairExcl;
    cur[2 * t + 1] = segStart + pairExcl + a0;
    __syncthreads();

    int rN = nNodes - r0; if (rN > PROWS) rN = PROWS;
    for (int j = t; j < rN; j += 1024) rowStart[r0 + j] = cur[j];
    if (p == nPart - 1 && t == 0) rowStart[nNodes] = nE;
    __syncthreads();

    for (int i = segStart + t; i < segEnd; i += 1024) {
        unsigned k = keyA[i];
        int lr = k >> 19;
        int pos = atomicAdd(&cur[lr], 1);
        csr[pos] = (((unsigned)valA[i]) << 19) | (k & 0x7FFFFu);
    }
}

// ---------------- convert concat(uE,iE) f32 -> bf16 (8 elems/thread) ----------
__global__ __launch_bounds__(256) void k_toBf16(const float* __restrict__ uE,
                                                const float* __restrict__ iE,
                                                ushort* __restrict__ embB,
                                                int nNodes, int nUsers) {
    const long total8 = (long)nNodes * DIM / 8;
    const long user8  = (long)nUsers * DIM / 8;
    for (long i = (long)blockIdx.x * blockDim.x + threadIdx.x; i < total8;
         i += (long)gridDim.x * blockDim.x) {
        const float4* p = (i < user8) ? (const float4*)uE + 2 * i
                                      : (const float4*)iE + 2 * (i - user8);
        float4 a = p[0], b = p[1];
        uint4 o;
        o.x = pk(a.x, a.y); o.y = pk(a.z, a.w);
        o.z = pk(b.x, b.y); o.w = pk(b.z, b.w);
        ((uint4*)embB)[i] = o;
    }
}

// ---------------- SpMM hop1 (bf16 gather, packed u32 edges) -------------------
__global__ __launch_bounds__(256) void k_spmm1(const int* __restrict__ rowStart,
                                               const unsigned* __restrict__ csr,
                                               const ushort* __restrict__ embB,
                                               ushort* __restrict__ cur1B,
                                               int nNodes) {
    const int lane = threadIdx.x & 63;
    int r = blockIdx.x * (blockDim.x >> 6) + (threadIdx.x >> 6);
    if (r >= nNodes) return;
    int start = __builtin_amdgcn_readfirstlane(rowStart[r]);
    int end   = __builtin_amdgcn_readfirstlane(rowStart[r + 1]);
    float acc = 0.f;
    int e = start;
    for (; e + 7 < end; e += 8) {
        unsigned k[8]; float x[8];
        #pragma unroll
        for (int j = 0; j < 8; ++j) k[j] = csr[e + j];
        #pragma unroll
        for (int j = 0; j < 8; ++j) x[j] = b2f(embB[(size_t)(k[j] & 0x7FFFFu) * DIM + lane]);
        #pragma unroll
        for (int j = 0; j < 8; ++j) acc = fmaf(decV(k[j]), x[j], acc);
    }
    for (; e + 3 < end; e += 4) {
        unsigned k[4]; float x[4];
        #pragma unroll
        for (int j = 0; j < 4; ++j) k[j] = csr[e + j];
        #pragma unroll
        for (int j = 0; j < 4; ++j) x[j] = b2f(embB[(size_t)(k[j] & 0x7FFFFu) * DIM + lane]);
        #pragma unroll
        for (int j = 0; j < 4; ++j) acc = fmaf(decV(k[j]), x[j], acc);
    }
    for (; e < end; ++e) {
        unsigned k = csr[e];
        acc = fmaf(decV(k), b2f(embB[(size_t)(k & 0x7FFFFu) * DIM + lane]), acc);
    }
    cur1B[(size_t)r * DIM + lane] = f2b(acc);
}

// ---------------- SpMM hop2 (bf16 gather) + fused epilogue --------------------
__global__ __launch_bounds__(256) void k_spmm2(const int* __restrict__ rowStart,
                                               const unsigned* __restrict__ csr,
                                               const ushort* __restrict__ cur1B,
                                               const ushort* __restrict__ embB,
                                               float* __restrict__ out,
                                               int nNodes) {
    const int lane = threadIdx.x & 63;
    int r = blockIdx.x * (blockDim.x >> 6) + (threadIdx.x >> 6);
    if (r >= nNodes) return;
    int start = __builtin_amdgcn_readfirstlane(rowStart[r]);
    int end   = __builtin_amdgcn_readfirstlane(rowStart[r + 1]);
    float acc = 0.f;
    int e = start;
    for (; e + 7 < end; e += 8) {
        unsigned k[8]; float x[8];
        #pragma unroll
        for (int j = 0; j < 8; ++j) k[j] = csr[e + j];
        #pragma unroll
        for (int j = 0; j < 8; ++j) x[j] = b2f(cur1B[(size_t)(k[j] & 0x7FFFFu) * DIM + lane]);
        #pragma unroll
        for (int j = 0; j < 8; ++j) acc = fmaf(decV(k[j]), x[j], acc);
    }
    for (; e + 3 < end; e += 4) {
        unsigned k[4]; float x[4];
        #pragma unroll
        for (int j = 0; j < 4; ++j) k[j] = csr[e + j];
        #pragma unroll
        for (int j = 0; j < 4; ++j) x[j] = b2f(cur1B[(size_t)(k[j] & 0x7FFFFu) * DIM + lane]);
        #pragma unroll
        for (int j = 0; j < 4; ++j) acc = fmaf(decV(k[j]), x[j], acc);
    }
    for (; e < end; ++e) {
        unsigned k = csr[e];
        acc = fmaf(decV(k), b2f(cur1B[(size_t)(k & 0x7FFFFu) * DIM + lane]), acc);
    }
    float em = b2f(embB[(size_t)r * DIM + lane]);
    float c1 = b2f(cur1B[(size_t)r * DIM + lane]);
    float o = (em + c1 + acc) * (1.0f / 3.0f);
    __builtin_nontemporal_store(o, &out[(size_t)r * DIM + lane]);
}

// ---------------- fallback (round-1 atomic path) ----------------
__global__ __launch_bounds__(256) void spmm_scatter(
    const int* __restrict__ rows, const int* __restrict__ cols,
    const float* __restrict__ vals, const float* __restrict__ srcU,
    const float* __restrict__ srcI, float* __restrict__ dst,
    float scale, int nEdges, int nUsers)
{
    const int lane = threadIdx.x & 63;
    const int wavesPerBlock = blockDim.x >> 6;
    long wave = (long)blockIdx.x * wavesPerBlock + (threadIdx.x >> 6);
    const long nWaves = (long)gridDim.x * wavesPerBlock;
    for (long e = wave; e < nEdges; e += nWaves) {
        const int r = rows[e];
        const int c = cols[e];
        const float v = vals[e] * scale;
        const float* src;
        if (srcI != nullptr) {
            src = (c < nUsers) ? (srcU + (size_t)c * DIM)
                               : (srcI + (size_t)(c - nUsers) * DIM);
        } else {
            src = srcU + (size_t)c * DIM;
        }
        atomicAdd(dst + (size_t)r * DIM + lane, v * src[lane]);
    }
}

__global__ __launch_bounds__(256) void finalize_base(
    const float* __restrict__ userE, const float* __restrict__ itemE,
    const float* __restrict__ cur1, float* __restrict__ out, int nNodes, int nUsers)
{
    const long total4 = (long)nNodes * DIM / 4;
    const long user4  = (long)nUsers * DIM / 4;
    const float inv3 = 1.0f / 3.0f;
    for (long i = (long)blockIdx.x * blockDim.x + threadIdx.x; i < total4;
         i += (long)gridDim.x * blockDim.x) {
        float4 e = (i < user4) ? ((const float4*)userE)[i]
                               : ((const float4*)itemE)[i - user4];
        float4 c = ((const float4*)cur1)[i];
        float4 o;
        o.x = (e.x + c.x) * inv3; o.y = (e.y + c.y) * inv3;
        o.z = (e.z + c.z) * inv3; o.w = (e.w + c.w) * inv3;
        ((float4*)out)[i] = o;
    }
}

// ----------------------------------------------------------------

static inline size_t align256(size_t x) { return (x + 255) & ~(size_t)255; }

extern "C" void kernel_launch(void* const* d_in, const int* in_sizes, int n_in,
                              void* d_out, int out_size, void* d_ws, size_t ws_size,
                              hipStream_t stream)
{
    const int*   rows  = (const int*)d_in[0];
    const int*   cols  = (const int*)d_in[1];
    const float* vals  = (const float*)d_in[2];
    const float* userE = (const float*)d_in[3];
    const float* itemE = (const float*)d_in[4];
    float* out = (float*)d_out;

    const int nE     = in_sizes[0];
    const int nUsers = in_sizes[3] / DIM;
    const int nItems = in_sizes[4] / DIM;
    const int nNodes = nUsers + nItems;
    const int nPart  = (nNodes + PROWS - 1) / PROWS;

    // ws layout:
    //   [region0: max(keyA+valA, embB+cur1B, cur1_f32-fallback)]
    //     keyA/valA live here during preprocessing; after buildCSR they are
    //     dead and k_toBf16/spmm1 overwrite the region with embB + cur1B.
    //   [csr (u32/edge)][rowStart][partStart][partCurPad][partCnt]
    const size_t embBB    = (size_t)nNodes * DIM * sizeof(ushort);   // 38.4 MB
    const size_t cur1BB   = (size_t)nNodes * DIM * sizeof(ushort);   // 38.4 MB
    const size_t cur1F32B = (size_t)nNodes * DIM * sizeof(float);    // fallback
    const size_t keyAB    = (size_t)nE * sizeof(unsigned);           // 32 MB
    const size_t valAOff  = align256(keyAB);
    const size_t soaB     = valAOff + (size_t)nE * sizeof(ushort);   // ~48 MB
    size_t reg0B = embBB + cur1BB;
    if (soaB     > reg0B) reg0B = soaB;
    if (cur1F32B > reg0B) reg0B = cur1F32B;
    const size_t csrOff   = align256(reg0B);
    const size_t csrB     = (size_t)nE * sizeof(unsigned);           // 32 MB
    const size_t rsOff    = align256(csrOff + csrB);
    const size_t rsB      = ((size_t)nNodes + 1) * sizeof(int);
    const size_t psOff    = align256(rsOff + rsB);
    const size_t psB      = ((size_t)MAXPART + 1) * sizeof(int);
    const size_t pcOff    = align256(psOff + psB);
    const size_t pcB      = (size_t)MAXPART * 16 * sizeof(int);
    const size_t cntOff   = align256(pcOff + pcB);
    const size_t cntB     = (size_t)MAXPART * sizeof(int);
    const size_t required = cntOff + cntB;

    char* ws = (char*)d_ws;
    unsigned* keyA    = (unsigned*)ws;               // preprocessing phase
    ushort*   valA    = (ushort*)(ws + valAOff);
    ushort*   embB    = (ushort*)ws;                 // after buildCSR
    ushort*   cur1B   = (ushort*)(ws + embBB);
    float*    cur1F32 = (float*)ws;                  // fallback only
    unsigned* csr     = (unsigned*)(ws + csrOff);

    if (ws_size >= required && nNodes <= MAXPART * PROWS && nNodes < (1 << 19)) {
        int* rowStart   = (int*)(ws + rsOff);
        int* partStart  = (int*)(ws + psOff);
        int* partCurPad = (int*)(ws + pcOff);
        int* partCnt    = (int*)(ws + cntOff);

        const int nChunks = (nE + SCHUNK - 1) / SCHUNK;

        hipMemsetAsync(partCnt, 0, (size_t)nPart * sizeof(int), stream);
        k_phist<<<dim3(512), dim3(256), 0, stream>>>(rows, partCnt, nE, nPart);
        k_pscan<<<dim3(1), dim3(256), 0, stream>>>(partCnt, partStart, partCurPad,
                                                   nPart, nE);
        k_scatterS<<<dim3(nChunks), dim3(256), 0, stream>>>(rows, cols, vals,
                                                            partCurPad, keyA, valA,
                                                            nE, nPart);
        k_buildCSR<<<dim3(nPart), dim3(1024), 0, stream>>>(partStart, keyA, valA, csr,
                                                           rowStart, nNodes, nE, nPart);
        // keyA/valA dead; overwrite region with bf16 node matrix
        k_toBf16<<<dim3(2048), dim3(256), 0, stream>>>(userE, itemE, embB,
                                                       nNodes, nUsers);

        const int rowsPerBlock = 4;
        dim3 sgrid((nNodes + rowsPerBlock - 1) / rowsPerBlock), sblk(256);
        k_spmm1<<<sgrid, sblk, 0, stream>>>(rowStart, csr, embB, cur1B, nNodes);
        k_spmm2<<<sgrid, sblk, 0, stream>>>(rowStart, csr, cur1B, embB, out, nNodes);
    } else {
        // fallback: atomic scatter path (round-1)
        hipMemsetAsync(cur1F32, 0, cur1F32B, stream);
        dim3 blk(256);
        spmm_scatter<<<dim3(4096), blk, 0, stream>>>(rows, cols, vals, userE, itemE,
                                                     cur1F32, 1.0f, nE, nUsers);
        finalize_base<<<dim3(2048), blk, 0, stream>>>(userE, itemE, cur1F32, out,
                                                      nNodes, nUsers);
        spmm_scatter<<<dim3(4096), blk, 0, stream>>>(rows, cols, vals, cur1F32, nullptr,
                                                     out, 1.0f / 3.0f, nE, nUsers);
    }
}